// Round 1
// baseline (2127.152 us; speedup 1.0000x reference)
//
#include <hip/hip_runtime.h>
#include <hip/hip_bf16.h>

#define NN 100000
#define NE 1600000
#define F 128
#define NCLS 47

// ---------- CSR build ----------
__global__ void k_deg(const int* __restrict__ dst, int* __restrict__ deg) {
    int e = blockIdx.x * blockDim.x + threadIdx.x;
    if (e < NE) atomicAdd(&deg[dst[e]], 1);
}

__global__ void __launch_bounds__(1024) k_scan(const int* __restrict__ deg,
                                               int* __restrict__ row_off,
                                               float* __restrict__ inv_deg) {
    __shared__ int part[1024];
    __shared__ int carry_s;
    const int t = threadIdx.x;
    if (t == 0) carry_s = 0;
    __syncthreads();
    const int VT = 8;
    const int CHUNK = 1024 * VT;
    for (int base = 0; base < NN; base += CHUNK) {
        int v[VT];
        int loc = 0;
        int i0 = base + t * VT;
#pragma unroll
        for (int j = 0; j < VT; j++) {
            int idx = i0 + j;
            v[j] = (idx < NN) ? deg[idx] : 0;
            loc += v[j];
        }
        int carry = carry_s;   // last write to carry_s was before a barrier
        part[t] = loc;
        __syncthreads();
        int run_inc = loc;
        for (int off = 1; off < 1024; off <<= 1) {
            int add = (t >= off) ? part[t - off] : 0;
            __syncthreads();
            run_inc += add;
            part[t] = run_inc;
            __syncthreads();
        }
        int excl = carry + run_inc - loc;
#pragma unroll
        for (int j = 0; j < VT; j++) {
            int idx = i0 + j;
            if (idx < NN) {
                row_off[idx] = excl;
                inv_deg[idx] = 1.0f / fmaxf((float)v[j], 1.0f);
                excl += v[j];
            }
        }
        __syncthreads();
        if (t == 1023) carry_s = carry + run_inc;
        __syncthreads();
    }
    if (t == 0) row_off[NN] = carry_s;
}

__global__ void k_fill(const int* __restrict__ src, const int* __restrict__ dst,
                       const int* __restrict__ row_off, int* __restrict__ cursor,
                       int* __restrict__ col) {
    int e = blockIdx.x * blockDim.x + threadIdx.x;
    if (e < NE) {
        int d = dst[e];
        int p = atomicAdd(&cursor[d], 1);
        col[row_off[d] + p] = src[e];
    }
}

// ---------- mean aggregation: one wave per node ----------
__global__ void __launch_bounds__(256) k_agg(const float* __restrict__ h,
                                             const int* __restrict__ row_off,
                                             const int* __restrict__ col,
                                             const float* __restrict__ inv_deg,
                                             float* __restrict__ agg) {
    int node = (blockIdx.x * blockDim.x + threadIdx.x) >> 6;
    int lane = threadIdx.x & 63;
    if (node >= NN) return;
    int b = row_off[node], e = row_off[node + 1];
    const float2* h2 = (const float2*)h;
    float2 acc = make_float2(0.f, 0.f);
    for (int j = b; j < e; j++) {
        int c = col[j];
        float2 v = h2[(size_t)c * 64 + lane];
        acc.x += v.x;
        acc.y += v.y;
    }
    float s = inv_deg[node];
    ((float2*)agg)[(size_t)node * 64 + lane] = make_float2(acc.x * s, acc.y * s);
}

// ---------- fused dual-GEMM layer (128 outputs): out = act(h@Ws + agg@Wn + b) ----------
template <bool RELU>
__global__ void __launch_bounds__(1024) k_layer128(const float* __restrict__ h,
                                                   const float* __restrict__ agg,
                                                   const float* __restrict__ Ws,
                                                   const float* __restrict__ Wn,
                                                   const float* __restrict__ b,
                                                   float* __restrict__ out,
                                                   int npb) {
    __shared__ float wlds[2][F][F];  // 128 KB
    {
        const float4* s4 = (const float4*)Ws;
        const float4* n4 = (const float4*)Wn;
        float4* d0 = (float4*)&wlds[0][0][0];
        float4* d1 = (float4*)&wlds[1][0][0];
        const int tot = F * F / 4;  // 4096
        for (int i = threadIdx.x; i < tot; i += 1024) d0[i] = s4[i];
        for (int i = threadIdx.x; i < tot; i += 1024) d1[i] = n4[i];
    }
    __syncthreads();
    const int wid = threadIdx.x >> 6, lane = threadIdx.x & 63;
    const int node0 = blockIdx.x * npb;
    const int nend = min(node0 + npb, NN);
    float2 bias = ((const float2*)b)[lane];
    const float2* wls = (const float2*)&wlds[0][0][0];
    const float2* wln = (const float2*)&wlds[1][0][0];
    for (int n = node0 + wid; n < nend; n += 16) {
        float2 hv = ((const float2*)h)[(size_t)n * 64 + lane];
        float2 av = ((const float2*)agg)[(size_t)n * 64 + lane];
        float2 acc = bias;
#pragma unroll 8
        for (int kk = 0; kk < 64; kk++) {
            float hx = __shfl(hv.x, kk), hy = __shfl(hv.y, kk);
            float ax = __shfl(av.x, kk), ay = __shfl(av.y, kk);
            float2 w;
            w = wls[(2 * kk) * 64 + lane];
            acc.x += hx * w.x; acc.y += hx * w.y;
            w = wls[(2 * kk + 1) * 64 + lane];
            acc.x += hy * w.x; acc.y += hy * w.y;
            w = wln[(2 * kk) * 64 + lane];
            acc.x += ax * w.x; acc.y += ax * w.y;
            w = wln[(2 * kk + 1) * 64 + lane];
            acc.x += ay * w.x; acc.y += ay * w.y;
        }
        if (RELU) {
            acc.x = fmaxf(acc.x, 0.f);
            acc.y = fmaxf(acc.y, 0.f);
        }
        ((float2*)out)[(size_t)n * 64 + lane] = acc;
    }
}

// ---------- final layer (47 outputs) + log_softmax ----------
__global__ void __launch_bounds__(1024) k_layer_out(const float* __restrict__ h,
                                                    const float* __restrict__ agg,
                                                    const float* __restrict__ Ws,
                                                    const float* __restrict__ Wn,
                                                    const float* __restrict__ b,
                                                    float* __restrict__ out,
                                                    int npb) {
    __shared__ float wlds[2][F][48];  // 48 KB
    for (int i = threadIdx.x; i < F * NCLS; i += 1024) {
        int k = i / NCLS, c = i % NCLS;
        wlds[0][k][c] = Ws[i];
        wlds[1][k][c] = Wn[i];
    }
    __syncthreads();
    const int wid = threadIdx.x >> 6, lane = threadIdx.x & 63;
    const int node0 = blockIdx.x * npb;
    const int nend = min(node0 + npb, NN);
    const int c = (lane < NCLS) ? lane : 0;
    float bias = (lane < NCLS) ? b[lane] : 0.f;
    for (int n = node0 + wid; n < nend; n += 16) {
        float2 hv = ((const float2*)h)[(size_t)n * 64 + lane];
        float2 av = ((const float2*)agg)[(size_t)n * 64 + lane];
        float acc = bias;
#pragma unroll 8
        for (int kk = 0; kk < 64; kk++) {
            float hx = __shfl(hv.x, kk), hy = __shfl(hv.y, kk);
            float ax = __shfl(av.x, kk), ay = __shfl(av.y, kk);
            acc += hx * wlds[0][2 * kk][c] + hy * wlds[0][2 * kk + 1][c] +
                   ax * wlds[1][2 * kk][c] + ay * wlds[1][2 * kk + 1][c];
        }
        // log_softmax over lanes 0..46
        float v = (lane < NCLS) ? acc : -INFINITY;
        float m = v;
        for (int off = 32; off; off >>= 1) m = fmaxf(m, __shfl_xor(m, off));
        float ex = (lane < NCLS) ? expf(acc - m) : 0.f;
        float ssum = ex;
        for (int off = 32; off; off >>= 1) ssum += __shfl_xor(ssum, off);
        float ls = acc - m - logf(ssum);
        if (lane < NCLS) out[(size_t)n * NCLS + lane] = ls;
    }
}

extern "C" void kernel_launch(void* const* d_in, const int* in_sizes, int n_in,
                              void* d_out, int out_size, void* d_ws, size_t ws_size,
                              hipStream_t stream) {
    (void)in_sizes; (void)n_in; (void)out_size; (void)ws_size;
    const float* x = (const float*)d_in[0];
    const int* src = (const int*)d_in[1];
    const int* dst = (const int*)d_in[2];
    const float* Ws0 = (const float*)d_in[3];
    const float* Wn0 = (const float*)d_in[4];
    const float* b0 = (const float*)d_in[5];
    const float* Ws1 = (const float*)d_in[6];
    const float* Wn1 = (const float*)d_in[7];
    const float* b1 = (const float*)d_in[8];
    const float* Ws2 = (const float*)d_in[9];
    const float* Wn2 = (const float*)d_in[10];
    const float* b2 = (const float*)d_in[11];
    float* out = (float*)d_out;

    char* w = (char*)d_ws;
    size_t off = 0;
    auto alloc = [&](size_t bytes) -> char* {
        char* p = w + off;
        off = (off + bytes + 255) & ~(size_t)255;
        return p;
    };
    int* deg = (int*)alloc((size_t)NN * 4);
    int* row_off = (int*)alloc((size_t)(NN + 1) * 4);
    int* cursor = (int*)alloc((size_t)NN * 4);
    int* col = (int*)alloc((size_t)NE * 4);
    float* inv_deg = (float*)alloc((size_t)NN * 4);
    float* aggb = (float*)alloc((size_t)NN * F * 4);
    float* h1 = (float*)alloc((size_t)NN * F * 4);
    float* h2 = (float*)alloc((size_t)NN * F * 4);

    hipMemsetAsync(deg, 0, (size_t)NN * 4, stream);
    hipMemsetAsync(cursor, 0, (size_t)NN * 4, stream);

    const int EB = (NE + 255) / 256;
    k_deg<<<EB, 256, 0, stream>>>(dst, deg);
    k_scan<<<1, 1024, 0, stream>>>(deg, row_off, inv_deg);
    k_fill<<<EB, 256, 0, stream>>>(src, dst, row_off, cursor, col);

    const int AGG_B = (NN * 64 + 255) / 256;  // wave per node
    const int NPB = 196;
    const int LB = (NN + NPB - 1) / NPB;  // 511 blocks
    const int NPB2 = 128;
    const int LB2 = (NN + NPB2 - 1) / NPB2;  // 782 blocks

    // layer 0
    k_agg<<<AGG_B, 256, 0, stream>>>(x, row_off, col, inv_deg, aggb);
    k_layer128<true><<<LB, 1024, 0, stream>>>(x, aggb, Ws0, Wn0, b0, h1, NPB);
    // layer 1
    k_agg<<<AGG_B, 256, 0, stream>>>(h1, row_off, col, inv_deg, aggb);
    k_layer128<true><<<LB, 1024, 0, stream>>>(h1, aggb, Ws1, Wn1, b1, h2, NPB);
    // layer 2
    k_agg<<<AGG_B, 256, 0, stream>>>(h2, row_off, col, inv_deg, aggb);
    k_layer_out<<<LB2, 1024, 0, stream>>>(h2, aggb, Ws2, Wn2, b2, out, NPB2);
}

// Round 2
// 883.265 us; speedup vs baseline: 2.4083x; 2.4083x over previous
//
#include <hip/hip_runtime.h>
#include <hip/hip_bf16.h>

#define NN 100000
#define NE 1600000
#define F 128
#define NCLS 47

typedef __attribute__((ext_vector_type(8))) short short8;
typedef __attribute__((ext_vector_type(8))) unsigned short u16x8;
typedef __attribute__((ext_vector_type(4))) float f32x4;

#define MFMA16(A, B, C) __builtin_amdgcn_mfma_f32_16x16x32_bf16(A, B, C, 0, 0, 0)

__device__ __forceinline__ unsigned short b16(float f) {
    unsigned int u = __builtin_bit_cast(unsigned int, f);
    unsigned int r = u + 0x7FFFu + ((u >> 16) & 1u);  // RTN-even
    return (unsigned short)(r >> 16);
}
__device__ __forceinline__ float bflo(unsigned int u) { return __builtin_bit_cast(float, u << 16); }
__device__ __forceinline__ float bfhi(unsigned int u) { return __builtin_bit_cast(float, u & 0xFFFF0000u); }

// ---------- CSR build ----------
__global__ void k_deg(const int* __restrict__ dst, int* __restrict__ deg) {
    int e = blockIdx.x * blockDim.x + threadIdx.x;
    if (e < NE) atomicAdd(&deg[dst[e]], 1);
}

__global__ void __launch_bounds__(1024) k_scan(const int* __restrict__ deg,
                                               int* __restrict__ row_off,
                                               float* __restrict__ inv_deg) {
    __shared__ int part[1024];
    __shared__ int carry_s;
    const int t = threadIdx.x;
    if (t == 0) carry_s = 0;
    __syncthreads();
    const int VT = 8;
    const int CHUNK = 1024 * VT;
    for (int base = 0; base < NN; base += CHUNK) {
        int v[VT];
        int loc = 0;
        int i0 = base + t * VT;
#pragma unroll
        for (int j = 0; j < VT; j++) {
            int idx = i0 + j;
            v[j] = (idx < NN) ? deg[idx] : 0;
            loc += v[j];
        }
        int carry = carry_s;
        part[t] = loc;
        __syncthreads();
        int run_inc = loc;
        for (int off = 1; off < 1024; off <<= 1) {
            int add = (t >= off) ? part[t - off] : 0;
            __syncthreads();
            run_inc += add;
            part[t] = run_inc;
            __syncthreads();
        }
        int excl = carry + run_inc - loc;
#pragma unroll
        for (int j = 0; j < VT; j++) {
            int idx = i0 + j;
            if (idx < NN) {
                row_off[idx] = excl;
                inv_deg[idx] = 1.0f / fmaxf((float)v[j], 1.0f);
                excl += v[j];
            }
        }
        __syncthreads();
        if (t == 1023) carry_s = carry + run_inc;
        __syncthreads();
    }
    if (t == 0) row_off[NN] = carry_s;
}

__global__ void k_fill(const int* __restrict__ src, const int* __restrict__ dst,
                       const int* __restrict__ row_off, int* __restrict__ cursor,
                       int* __restrict__ col) {
    int e = blockIdx.x * blockDim.x + threadIdx.x;
    if (e < NE) {
        int d = dst[e];
        int p = atomicAdd(&cursor[d], 1);
        col[row_off[d] + p] = src[e];
    }
}

// ---------- fp32 -> bf16 convert (x) ----------
__global__ void k_cvt(const float* __restrict__ x, unsigned short* __restrict__ xb) {
    int t = blockIdx.x * blockDim.x + threadIdx.x;
    if (t >= NN * F / 8) return;
    const float4* x4 = (const float4*)x;
    float4 a = x4[t * 2], b = x4[t * 2 + 1];
    u16x8 o;
    o[0] = b16(a.x); o[1] = b16(a.y); o[2] = b16(a.z); o[3] = b16(a.w);
    o[4] = b16(b.x); o[5] = b16(b.y); o[6] = b16(b.z); o[7] = b16(b.w);
    ((u16x8*)xb)[t] = o;
}

// ---------- pack weights into MFMA-fragment-linear bf16 ----------
// layout per matrix: [nt][kk][lane][j], element = W[kk*32+(lane>>4)*8+j][nt*16+(lane&15)]
// bases (bf16 elems): Ws0:0 Wn0:16384 Ws1:32768 Wn1:49152 Ws2:65536 Wn2:71680 (tot 77824)
__global__ void k_pack_all(const float* __restrict__ Ws0, const float* __restrict__ Wn0,
                           const float* __restrict__ Ws1, const float* __restrict__ Wn1,
                           const float* __restrict__ Ws2, const float* __restrict__ Wn2,
                           unsigned short* __restrict__ wp) {
    int idx = blockIdx.x * blockDim.x + threadIdx.x;
    if (idx >= 77824) return;
    const float* W;
    int base, ncols;
    if (idx < 65536) {
        int m = idx >> 14;
        W = (m == 0) ? Ws0 : (m == 1) ? Wn0 : (m == 2) ? Ws1 : Wn1;
        base = m << 14;
        ncols = 128;
    } else {
        int m = (idx - 65536) / 6144;
        W = m ? Wn2 : Ws2;
        base = 65536 + m * 6144;
        ncols = NCLS;
    }
    int li = idx - base;
    int nt = li >> 11;
    int r = li & 2047;
    int kk = r >> 9;
    int r2 = r & 511;
    int lane = r2 >> 3;
    int j = r2 & 7;
    int k = kk * 32 + ((lane >> 4) << 3) + j;
    int n = nt * 16 + (lane & 15);
    float v = (n < ncols) ? W[k * ncols + n] : 0.f;
    wp[idx] = b16(v);
}

// ---------- mean aggregation over bf16 table, fp32 accum, bf16 out ----------
__global__ void __launch_bounds__(256) k_aggb(const unsigned int* __restrict__ hb32,
                                              const int* __restrict__ row_off,
                                              const int* __restrict__ col,
                                              const float* __restrict__ inv_deg,
                                              unsigned int* __restrict__ ab32) {
    int node = (blockIdx.x * blockDim.x + threadIdx.x) >> 6;
    int lane = threadIdx.x & 63;
    if (node >= NN) return;
    int b = row_off[node], e = row_off[node + 1];
    float ax = 0.f, ay = 0.f;
    for (int j = b; j < e; j++) {
        int c = col[j];
        unsigned int u = hb32[(size_t)c * 64 + lane];
        ax += bflo(u);
        ay += bfhi(u);
    }
    float s = inv_deg[node];
    ax *= s; ay *= s;
    ab32[(size_t)node * 64 + lane] = (unsigned int)b16(ax) | ((unsigned int)b16(ay) << 16);
}

// ---------- fused dual-GEMM layer via MFMA: out = act(h@Ws + agg@Wn + b), bf16 out ----------
// block = 256 thr = 4 waves (1x4), tile BM=64 x BN=128; wave tile 64x32 (M_rep=4, N_rep=2)
template <bool RELU>
__global__ void __launch_bounds__(256) k_layer(const unsigned short* __restrict__ hb,
                                               const unsigned short* __restrict__ ab,
                                               const unsigned short* __restrict__ wps,
                                               const unsigned short* __restrict__ wpn,
                                               const float* __restrict__ bias,
                                               unsigned short* __restrict__ outb) {
    const int wid = threadIdx.x >> 6, lane = threadIdx.x & 63;
    const int tile0 = blockIdx.x * 64;
    const short8* ws8 = (const short8*)wps;
    const short8* wn8 = (const short8*)wpn;
    short8 wf[2][2][4];
#pragma unroll
    for (int t = 0; t < 2; t++) {
        int nt = 2 * wid + t;
#pragma unroll
        for (int kk = 0; kk < 4; kk++) {
            wf[0][t][kk] = ws8[(nt * 4 + kk) * 64 + lane];
            wf[1][t][kk] = wn8[(nt * 4 + kk) * 64 + lane];
        }
    }
    const int rb = lane & 15, kq = lane >> 4;
    float bv[2];
#pragma unroll
    for (int t = 0; t < 2; t++) bv[t] = bias[(2 * wid + t) * 16 + rb];
    const short8* h8 = (const short8*)hb;
    const short8* a8 = (const short8*)ab;
    f32x4 zero = {0.f, 0.f, 0.f, 0.f};
    f32x4 acc[4][2];
#pragma unroll
    for (int m = 0; m < 4; m++)
#pragma unroll
        for (int t = 0; t < 2; t++) acc[m][t] = zero;
#pragma unroll
    for (int kk = 0; kk < 4; kk++) {
#pragma unroll
        for (int m = 0; m < 4; m++) {
            int row = tile0 + m * 16 + rb;
            int rc = row < NN ? row : NN - 1;
            int idx = rc * 16 + kk * 4 + kq;
            short8 af = h8[idx];
            short8 gf = a8[idx];
            acc[m][0] = MFMA16(af, wf[0][0][kk], acc[m][0]);
            acc[m][1] = MFMA16(af, wf[0][1][kk], acc[m][1]);
            acc[m][0] = MFMA16(gf, wf[1][0][kk], acc[m][0]);
            acc[m][1] = MFMA16(gf, wf[1][1][kk], acc[m][1]);
        }
    }
#pragma unroll
    for (int m = 0; m < 4; m++) {
#pragma unroll
        for (int reg = 0; reg < 4; reg++) {
            int row = tile0 + m * 16 + kq * 4 + reg;
            if (row < NN) {
#pragma unroll
                for (int t = 0; t < 2; t++) {
                    float v = acc[m][t][reg] + bv[t];
                    if (RELU) v = fmaxf(v, 0.f);
                    outb[(size_t)row * F + (2 * wid + t) * 16 + rb] = b16(v);
                }
            }
        }
    }
}

// ---------- final layer: MFMA (N=48, col47 padded) + log_softmax, fp32 out ----------
// block = 512 thr = 8 waves, each wave 16 rows x 48 cols (N_rep=3)
__global__ void __launch_bounds__(512) k_out(const unsigned short* __restrict__ hb,
                                             const unsigned short* __restrict__ ab,
                                             const unsigned short* __restrict__ wps,
                                             const unsigned short* __restrict__ wpn,
                                             const float* __restrict__ bias,
                                             float* __restrict__ out) {
    const int wid = threadIdx.x >> 6, lane = threadIdx.x & 63;
    const int R0 = blockIdx.x * 128 + wid * 16;
    const short8* ws8 = (const short8*)wps;
    const short8* wn8 = (const short8*)wpn;
    short8 wf[2][3][4];
#pragma unroll
    for (int nt = 0; nt < 3; nt++)
#pragma unroll
        for (int kk = 0; kk < 4; kk++) {
            wf[0][nt][kk] = ws8[(nt * 4 + kk) * 64 + lane];
            wf[1][nt][kk] = wn8[(nt * 4 + kk) * 64 + lane];
        }
    const int rb = lane & 15, kq = lane >> 4;
    float bv[3];
    bool valid[3];
#pragma unroll
    for (int nt = 0; nt < 3; nt++) {
        int c = nt * 16 + rb;
        valid[nt] = c < NCLS;
        bv[nt] = valid[nt] ? bias[c] : 0.f;
    }
    const short8* h8 = (const short8*)hb;
    const short8* a8 = (const short8*)ab;
    f32x4 zero = {0.f, 0.f, 0.f, 0.f};
    f32x4 acc[3] = {zero, zero, zero};
    int rowr = R0 + rb;
    int rc = rowr < NN ? rowr : NN - 1;
#pragma unroll
    for (int kk = 0; kk < 4; kk++) {
        int idx = rc * 16 + kk * 4 + kq;
        short8 af = h8[idx];
        short8 gf = a8[idx];
#pragma unroll
        for (int nt = 0; nt < 3; nt++) {
            acc[nt] = MFMA16(af, wf[0][nt][kk], acc[nt]);
            acc[nt] = MFMA16(gf, wf[1][nt][kk], acc[nt]);
        }
    }
#pragma unroll
    for (int reg = 0; reg < 4; reg++) {
        int row = R0 + kq * 4 + reg;
        float v[3];
        float mx = -1e30f;
#pragma unroll
        for (int nt = 0; nt < 3; nt++) {
            v[nt] = acc[nt][reg] + bv[nt];
            if (valid[nt]) mx = fmaxf(mx, v[nt]);
        }
        for (int off = 1; off < 16; off <<= 1) mx = fmaxf(mx, __shfl_xor(mx, off));
        float s = 0.f;
#pragma unroll
        for (int nt = 0; nt < 3; nt++)
            if (valid[nt]) s += expf(v[nt] - mx);
        for (int off = 1; off < 16; off <<= 1) s += __shfl_xor(s, off);
        float L = mx + logf(s);
        if (row < NN) {
#pragma unroll
            for (int nt = 0; nt < 3; nt++)
                if (valid[nt]) out[(size_t)row * NCLS + nt * 16 + rb] = v[nt] - L;
        }
    }
}

extern "C" void kernel_launch(void* const* d_in, const int* in_sizes, int n_in,
                              void* d_out, int out_size, void* d_ws, size_t ws_size,
                              hipStream_t stream) {
    (void)in_sizes; (void)n_in; (void)out_size; (void)ws_size;
    const float* x = (const float*)d_in[0];
    const int* src = (const int*)d_in[1];
    const int* dst = (const int*)d_in[2];
    const float* Ws0 = (const float*)d_in[3];
    const float* Wn0 = (const float*)d_in[4];
    const float* b0 = (const float*)d_in[5];
    const float* Ws1 = (const float*)d_in[6];
    const float* Wn1 = (const float*)d_in[7];
    const float* b1 = (const float*)d_in[8];
    const float* Ws2 = (const float*)d_in[9];
    const float* Wn2 = (const float*)d_in[10];
    const float* b2 = (const float*)d_in[11];
    float* out = (float*)d_out;

    char* w = (char*)d_ws;
    size_t off = 0;
    auto alloc = [&](size_t bytes) -> char* {
        char* p = w + off;
        off = (off + bytes + 255) & ~(size_t)255;
        return p;
    };
    int* deg = (int*)alloc((size_t)NN * 4);
    int* row_off = (int*)alloc((size_t)(NN + 1) * 4);
    int* cursor = (int*)alloc((size_t)NN * 4);
    int* col = (int*)alloc((size_t)NE * 4);
    float* inv_deg = (float*)alloc((size_t)NN * 4);
    unsigned short* xb = (unsigned short*)alloc((size_t)NN * F * 2);
    unsigned short* aggb = (unsigned short*)alloc((size_t)NN * F * 2);
    unsigned short* h1b = (unsigned short*)alloc((size_t)NN * F * 2);
    unsigned short* h2b = (unsigned short*)alloc((size_t)NN * F * 2);
    unsigned short* wp = (unsigned short*)alloc((size_t)77824 * 2);

    hipMemsetAsync(deg, 0, (size_t)NN * 4, stream);
    hipMemsetAsync(cursor, 0, (size_t)NN * 4, stream);

    const int EB = (NE + 255) / 256;
    k_deg<<<EB, 256, 0, stream>>>(dst, deg);
    k_scan<<<1, 1024, 0, stream>>>(deg, row_off, inv_deg);
    k_fill<<<EB, 256, 0, stream>>>(src, dst, row_off, cursor, col);
    k_cvt<<<(NN * F / 8 + 255) / 256, 256, 0, stream>>>(x, xb);
    k_pack_all<<<(77824 + 255) / 256, 256, 0, stream>>>(Ws0, Wn0, Ws1, Wn1, Ws2, Wn2, wp);

    unsigned short* wS0 = wp;
    unsigned short* wN0 = wp + 16384;
    unsigned short* wS1 = wp + 32768;
    unsigned short* wN1 = wp + 49152;
    unsigned short* wS2 = wp + 65536;
    unsigned short* wN2 = wp + 71680;

    const int AGG_B = NN * 64 / 256;            // 25000 (wave per node)
    const int LYR_B = (NN + 63) / 64;           // 1563
    const int OUT_B = (NN + 127) / 128;         // 782

    // layer 0
    k_aggb<<<AGG_B, 256, 0, stream>>>((const unsigned int*)xb, row_off, col, inv_deg,
                                      (unsigned int*)aggb);
    k_layer<true><<<LYR_B, 256, 0, stream>>>(xb, aggb, wS0, wN0, b0, h1b);
    // layer 1
    k_aggb<<<AGG_B, 256, 0, stream>>>((const unsigned int*)h1b, row_off, col, inv_deg,
                                      (unsigned int*)aggb);
    k_layer<true><<<LYR_B, 256, 0, stream>>>(h1b, aggb, wS1, wN1, b1, h2b);
    // layer 2
    k_aggb<<<AGG_B, 256, 0, stream>>>((const unsigned int*)h2b, row_off, col, inv_deg,
                                      (unsigned int*)aggb);
    k_out<<<OUT_B, 512, 0, stream>>>(h2b, aggb, wS2, wN2, b2, out);
}

// Round 3
// 597.075 us; speedup vs baseline: 3.5626x; 1.4793x over previous
//
#include <hip/hip_runtime.h>
#include <hip/hip_bf16.h>

#define NN 100000
#define NE 1600000
#define F 128
#define NCLS 47

typedef __attribute__((ext_vector_type(8))) short short8;
typedef __attribute__((ext_vector_type(8))) unsigned short u16x8;
typedef __attribute__((ext_vector_type(4))) float f32x4;

#define MFMA16(A, B, C) __builtin_amdgcn_mfma_f32_16x16x32_bf16(A, B, C, 0, 0, 0)

__device__ __forceinline__ unsigned short b16(float f) {
    unsigned int u = __builtin_bit_cast(unsigned int, f);
    unsigned int r = u + 0x7FFFu + ((u >> 16) & 1u);  // RTN-even
    return (unsigned short)(r >> 16);
}
__device__ __forceinline__ float bflo(unsigned int u) { return __builtin_bit_cast(float, u << 16); }
__device__ __forceinline__ float bfhi(unsigned int u) { return __builtin_bit_cast(float, u & 0xFFFF0000u); }

// ---------- CSR build ----------
__global__ void k_deg(const int* __restrict__ dst, int* __restrict__ deg) {
    int e = blockIdx.x * blockDim.x + threadIdx.x;
    if (e < NE) atomicAdd(&deg[dst[e]], 1);
}

// 1-block scan: wave-shuffle inclusive scan + cross-wave combine (3 barriers/chunk)
__global__ void __launch_bounds__(1024) k_scan(const int* __restrict__ deg,
                                               int* __restrict__ row_off,
                                               float* __restrict__ inv_deg) {
    __shared__ int wsum[16];
    __shared__ int carry_s;
    const int t = threadIdx.x, wid = t >> 6, lane = t & 63;
    if (t == 0) carry_s = 0;
    __syncthreads();
    const int VT = 8;
    const int CHUNK = 1024 * VT;
    for (int base = 0; base < NN; base += CHUNK) {
        int v[VT];
        int loc = 0;
        int i0 = base + t * VT;
#pragma unroll
        for (int j = 0; j < VT; j++) {
            int idx = i0 + j;
            v[j] = (idx < NN) ? deg[idx] : 0;
            loc += v[j];
        }
        // inclusive scan of loc within wave
        int run = loc;
#pragma unroll
        for (int off = 1; off < 64; off <<= 1) {
            int n = __shfl_up(run, off);
            if (lane >= off) run += n;
        }
        if (lane == 63) wsum[wid] = run;
        __syncthreads();
        int woff = carry_s;
        for (int wv = 0; wv < wid; wv++) woff += wsum[wv];
        int excl = woff + run - loc;
#pragma unroll
        for (int j = 0; j < VT; j++) {
            int idx = i0 + j;
            if (idx < NN) {
                row_off[idx] = excl;
                inv_deg[idx] = 1.0f / fmaxf((float)v[j], 1.0f);
                excl += v[j];
            }
        }
        __syncthreads();
        if (t == 1023) carry_s = woff + run;
        __syncthreads();
    }
    if (t == 0) row_off[NN] = carry_s;
}

__global__ void k_fill(const int* __restrict__ src, const int* __restrict__ dst,
                       const int* __restrict__ row_off, int* __restrict__ cursor,
                       int* __restrict__ col) {
    int e = blockIdx.x * blockDim.x + threadIdx.x;
    if (e < NE) {
        int d = dst[e];
        int p = atomicAdd(&cursor[d], 1);
        col[row_off[d] + p] = src[e];
    }
}

// ---------- fp32 -> bf16 convert (x) ----------
__global__ void k_cvt(const float* __restrict__ x, unsigned short* __restrict__ xb) {
    int t = blockIdx.x * blockDim.x + threadIdx.x;
    if (t >= NN * F / 8) return;
    const float4* x4 = (const float4*)x;
    float4 a = x4[t * 2], b = x4[t * 2 + 1];
    u16x8 o;
    o[0] = b16(a.x); o[1] = b16(a.y); o[2] = b16(a.z); o[3] = b16(a.w);
    o[4] = b16(b.x); o[5] = b16(b.y); o[6] = b16(b.z); o[7] = b16(b.w);
    ((u16x8*)xb)[t] = o;
}

// ---------- pack weights into MFMA-fragment-linear bf16 ----------
__global__ void k_pack_all(const float* __restrict__ Ws0, const float* __restrict__ Wn0,
                           const float* __restrict__ Ws1, const float* __restrict__ Wn1,
                           const float* __restrict__ Ws2, const float* __restrict__ Wn2,
                           unsigned short* __restrict__ wp) {
    int idx = blockIdx.x * blockDim.x + threadIdx.x;
    if (idx >= 77824) return;
    const float* W;
    int base, ncols;
    if (idx < 65536) {
        int m = idx >> 14;
        W = (m == 0) ? Ws0 : (m == 1) ? Wn0 : (m == 2) ? Ws1 : Wn1;
        base = m << 14;
        ncols = 128;
    } else {
        int m = (idx - 65536) / 6144;
        W = m ? Wn2 : Ws2;
        base = 65536 + m * 6144;
        ncols = NCLS;
    }
    int li = idx - base;
    int nt = li >> 11;
    int r = li & 2047;
    int kk = r >> 9;
    int r2 = r & 511;
    int lane = r2 >> 3;
    int j = r2 & 7;
    int k = kk * 32 + ((lane >> 4) << 3) + j;
    int n = nt * 16 + (lane & 15);
    float v = (n < ncols) ? W[k * ncols + n] : 0.f;
    wp[idx] = b16(v);
}

// ---------- mean aggregation: wave/node, col prefetch + shfl broadcast, MLP x8 ----------
__global__ void __launch_bounds__(256) k_aggb(const unsigned int* __restrict__ hb32,
                                              const int* __restrict__ row_off,
                                              const int* __restrict__ col,
                                              const float* __restrict__ inv_deg,
                                              unsigned int* __restrict__ ab32) {
    int node = (blockIdx.x * blockDim.x + threadIdx.x) >> 6;
    int lane = threadIdx.x & 63;
    if (node >= NN) return;
    int b = row_off[node], e = row_off[node + 1];
    int deg = e - b;
    float ax = 0.f, ay = 0.f;
    for (int base = 0; base < deg; base += 64) {
        int cnt = deg - base;
        if (cnt > 64) cnt = 64;
        int myc = col[b + base + (lane < cnt ? lane : 0)];
        for (int jj = 0; jj < cnt; jj += 8) {
            int cs[8];
            unsigned int us[8];
#pragma unroll
            for (int k = 0; k < 8; k++) {
                int idx = jj + k;
                cs[k] = __shfl(myc, idx < cnt ? idx : 0);
            }
#pragma unroll
            for (int k = 0; k < 8; k++) us[k] = hb32[(size_t)cs[k] * 64 + lane];
#pragma unroll
            for (int k = 0; k < 8; k++) {
                if (jj + k < cnt) {  // wave-uniform
                    ax += bflo(us[k]);
                    ay += bfhi(us[k]);
                }
            }
        }
    }
    float s = inv_deg[node];
    ax *= s; ay *= s;
    ab32[(size_t)node * 64 + lane] = (unsigned int)b16(ax) | ((unsigned int)b16(ay) << 16);
}

// ---------- fused dual-GEMM layer via MFMA ----------
template <bool RELU>
__global__ void __launch_bounds__(256) k_layer(const unsigned short* __restrict__ hb,
                                               const unsigned short* __restrict__ ab,
                                               const unsigned short* __restrict__ wps,
                                               const unsigned short* __restrict__ wpn,
                                               const float* __restrict__ bias,
                                               unsigned short* __restrict__ outb) {
    const int wid = threadIdx.x >> 6, lane = threadIdx.x & 63;
    const int tile0 = blockIdx.x * 64;
    const short8* ws8 = (const short8*)wps;
    const short8* wn8 = (const short8*)wpn;
    short8 wf[2][2][4];
#pragma unroll
    for (int t = 0; t < 2; t++) {
        int nt = 2 * wid + t;
#pragma unroll
        for (int kk = 0; kk < 4; kk++) {
            wf[0][t][kk] = ws8[(nt * 4 + kk) * 64 + lane];
            wf[1][t][kk] = wn8[(nt * 4 + kk) * 64 + lane];
        }
    }
    const int rb = lane & 15, kq = lane >> 4;
    float bv[2];
#pragma unroll
    for (int t = 0; t < 2; t++) bv[t] = bias[(2 * wid + t) * 16 + rb];
    const short8* h8 = (const short8*)hb;
    const short8* a8 = (const short8*)ab;
    f32x4 zero = {0.f, 0.f, 0.f, 0.f};
    f32x4 acc[4][2];
#pragma unroll
    for (int m = 0; m < 4; m++)
#pragma unroll
        for (int t = 0; t < 2; t++) acc[m][t] = zero;
#pragma unroll
    for (int kk = 0; kk < 4; kk++) {
#pragma unroll
        for (int m = 0; m < 4; m++) {
            int row = tile0 + m * 16 + rb;
            int rc = row < NN ? row : NN - 1;
            int idx = rc * 16 + kk * 4 + kq;
            short8 af = h8[idx];
            short8 gf = a8[idx];
            acc[m][0] = MFMA16(af, wf[0][0][kk], acc[m][0]);
            acc[m][1] = MFMA16(af, wf[0][1][kk], acc[m][1]);
            acc[m][0] = MFMA16(gf, wf[1][0][kk], acc[m][0]);
            acc[m][1] = MFMA16(gf, wf[1][1][kk], acc[m][1]);
        }
    }
#pragma unroll
    for (int m = 0; m < 4; m++) {
#pragma unroll
        for (int reg = 0; reg < 4; reg++) {
            int row = tile0 + m * 16 + kq * 4 + reg;
            if (row < NN) {
#pragma unroll
                for (int t = 0; t < 2; t++) {
                    float v = acc[m][t][reg] + bv[t];
                    if (RELU) v = fmaxf(v, 0.f);
                    outb[(size_t)row * F + (2 * wid + t) * 16 + rb] = b16(v);
                }
            }
        }
    }
}

// ---------- final layer: MFMA (N=48) + log_softmax, fp32 out ----------
__global__ void __launch_bounds__(512) k_out(const unsigned short* __restrict__ hb,
                                             const unsigned short* __restrict__ ab,
                                             const unsigned short* __restrict__ wps,
                                             const unsigned short* __restrict__ wpn,
                                             const float* __restrict__ bias,
                                             float* __restrict__ out) {
    const int wid = threadIdx.x >> 6, lane = threadIdx.x & 63;
    const int R0 = blockIdx.x * 128 + wid * 16;
    const short8* ws8 = (const short8*)wps;
    const short8* wn8 = (const short8*)wpn;
    short8 wf[2][3][4];
#pragma unroll
    for (int nt = 0; nt < 3; nt++)
#pragma unroll
        for (int kk = 0; kk < 4; kk++) {
            wf[0][nt][kk] = ws8[(nt * 4 + kk) * 64 + lane];
            wf[1][nt][kk] = wn8[(nt * 4 + kk) * 64 + lane];
        }
    const int rb = lane & 15, kq = lane >> 4;
    float bv[3];
    bool valid[3];
#pragma unroll
    for (int nt = 0; nt < 3; nt++) {
        int c = nt * 16 + rb;
        valid[nt] = c < NCLS;
        bv[nt] = valid[nt] ? bias[c] : 0.f;
    }
    const short8* h8 = (const short8*)hb;
    const short8* a8 = (const short8*)ab;
    f32x4 zero = {0.f, 0.f, 0.f, 0.f};
    f32x4 acc[3] = {zero, zero, zero};
    int rowr = R0 + rb;
    int rc = rowr < NN ? rowr : NN - 1;
#pragma unroll
    for (int kk = 0; kk < 4; kk++) {
        int idx = rc * 16 + kk * 4 + kq;
        short8 af = h8[idx];
        short8 gf = a8[idx];
#pragma unroll
        for (int nt = 0; nt < 3; nt++) {
            acc[nt] = MFMA16(af, wf[0][nt][kk], acc[nt]);
            acc[nt] = MFMA16(gf, wf[1][nt][kk], acc[nt]);
        }
    }
#pragma unroll
    for (int reg = 0; reg < 4; reg++) {
        int row = R0 + kq * 4 + reg;
        float v[3];
        float mx = -1e30f;
#pragma unroll
        for (int nt = 0; nt < 3; nt++) {
            v[nt] = acc[nt][reg] + bv[nt];
            if (valid[nt]) mx = fmaxf(mx, v[nt]);
        }
        for (int off = 1; off < 16; off <<= 1) mx = fmaxf(mx, __shfl_xor(mx, off));
        float s = 0.f;
#pragma unroll
        for (int nt = 0; nt < 3; nt++)
            if (valid[nt]) s += expf(v[nt] - mx);
        for (int off = 1; off < 16; off <<= 1) s += __shfl_xor(s, off);
        float L = mx + logf(s);
        if (row < NN) {
#pragma unroll
            for (int nt = 0; nt < 3; nt++)
                if (valid[nt]) out[(size_t)row * NCLS + nt * 16 + rb] = v[nt] - L;
        }
    }
}

extern "C" void kernel_launch(void* const* d_in, const int* in_sizes, int n_in,
                              void* d_out, int out_size, void* d_ws, size_t ws_size,
                              hipStream_t stream) {
    (void)in_sizes; (void)n_in; (void)out_size; (void)ws_size;
    const float* x = (const float*)d_in[0];
    const int* src = (const int*)d_in[1];
    const int* dst = (const int*)d_in[2];
    const float* Ws0 = (const float*)d_in[3];
    const float* Wn0 = (const float*)d_in[4];
    const float* b0 = (const float*)d_in[5];
    const float* Ws1 = (const float*)d_in[6];
    const float* Wn1 = (const float*)d_in[7];
    const float* b1 = (const float*)d_in[8];
    const float* Ws2 = (const float*)d_in[9];
    const float* Wn2 = (const float*)d_in[10];
    const float* b2 = (const float*)d_in[11];
    float* out = (float*)d_out;

    char* w = (char*)d_ws;
    size_t off = 0;
    auto alloc = [&](size_t bytes) -> char* {
        char* p = w + off;
        off = (off + bytes + 255) & ~(size_t)255;
        return p;
    };
    int* deg = (int*)alloc((size_t)NN * 4);
    int* row_off = (int*)alloc((size_t)(NN + 1) * 4);
    int* cursor = (int*)alloc((size_t)NN * 4);
    int* col = (int*)alloc((size_t)NE * 4);
    float* inv_deg = (float*)alloc((size_t)NN * 4);
    unsigned short* xb = (unsigned short*)alloc((size_t)NN * F * 2);
    unsigned short* aggb = (unsigned short*)alloc((size_t)NN * F * 2);
    unsigned short* h1b = (unsigned short*)alloc((size_t)NN * F * 2);
    unsigned short* h2b = (unsigned short*)alloc((size_t)NN * F * 2);
    unsigned short* wp = (unsigned short*)alloc((size_t)77824 * 2);

    hipMemsetAsync(deg, 0, (size_t)NN * 4, stream);
    hipMemsetAsync(cursor, 0, (size_t)NN * 4, stream);

    const int EB = (NE + 255) / 256;
    k_deg<<<EB, 256, 0, stream>>>(dst, deg);
    k_scan<<<1, 1024, 0, stream>>>(deg, row_off, inv_deg);
    k_fill<<<EB, 256, 0, stream>>>(src, dst, row_off, cursor, col);
    k_cvt<<<(NN * F / 8 + 255) / 256, 256, 0, stream>>>(x, xb);
    k_pack_all<<<(77824 + 255) / 256, 256, 0, stream>>>(Ws0, Wn0, Ws1, Wn1, Ws2, Wn2, wp);

    unsigned short* wS0 = wp;
    unsigned short* wN0 = wp + 16384;
    unsigned short* wS1 = wp + 32768;
    unsigned short* wN1 = wp + 49152;
    unsigned short* wS2 = wp + 65536;
    unsigned short* wN2 = wp + 71680;

    const int AGG_B = NN * 64 / 256;            // 25000 (wave per node)
    const int LYR_B = (NN + 63) / 64;           // 1563
    const int OUT_B = (NN + 127) / 128;         // 782

    // layer 0
    k_aggb<<<AGG_B, 256, 0, stream>>>((const unsigned int*)xb, row_off, col, inv_deg,
                                      (unsigned int*)aggb);
    k_layer<true><<<LYR_B, 256, 0, stream>>>(xb, aggb, wS0, wN0, b0, h1b);
    // layer 1
    k_aggb<<<AGG_B, 256, 0, stream>>>((const unsigned int*)h1b, row_off, col, inv_deg,
                                      (unsigned int*)aggb);
    k_layer<true><<<LYR_B, 256, 0, stream>>>(h1b, aggb, wS1, wN1, b1, h2b);
    // layer 2
    k_aggb<<<AGG_B, 256, 0, stream>>>((const unsigned int*)h2b, row_off, col, inv_deg,
                                      (unsigned int*)aggb);
    k_out<<<OUT_B, 512, 0, stream>>>(h2b, aggb, wS2, wN2, b2, out);
}

// Round 6
// 468.949 us; speedup vs baseline: 4.5360x; 1.2732x over previous
//
#include <hip/hip_runtime.h>
#include <hip/hip_bf16.h>

#define NN 100000
#define NE 1600000
#define F 128
#define NCLS 47

#define SCAN_B 98  // ceil(NN / 1024)

typedef __attribute__((ext_vector_type(8))) short short8;
typedef __attribute__((ext_vector_type(8))) unsigned short u16x8;
typedef __attribute__((ext_vector_type(4))) float f32x4;

#define MFMA16(A, B, C) __builtin_amdgcn_mfma_f32_16x16x32_bf16(A, B, C, 0, 0, 0)

__device__ __forceinline__ unsigned short b16(float f) {
    unsigned int u = __builtin_bit_cast(unsigned int, f);
    unsigned int r = u + 0x7FFFu + ((u >> 16) & 1u);  // RTN-even
    return (unsigned short)(r >> 16);
}
__device__ __forceinline__ float bflo(unsigned int u) { return __builtin_bit_cast(float, u << 16); }
__device__ __forceinline__ float bfhi(unsigned int u) { return __builtin_bit_cast(float, u & 0xFFFF0000u); }

// ---------- CSR build ----------
__global__ void k_deg(const int* __restrict__ dst, int* __restrict__ deg) {
    int e = blockIdx.x * blockDim.x + threadIdx.x;
    if (e < NE) atomicAdd(&deg[dst[e]], 1);
}

// hierarchical scan, stage 1: per-block (1024-elem chunk) totals
__global__ void __launch_bounds__(256) k_part(const int* __restrict__ deg,
                                              int* __restrict__ partials) {
    __shared__ int ws[4];
    const int t = threadIdx.x, lane = t & 63, wid = t >> 6;
    int i0 = blockIdx.x * 1024 + t * 4;
    int s = 0;
    if (i0 + 3 < NN) {
        int4 v = *(const int4*)&deg[i0];
        s = v.x + v.y + v.z + v.w;
    } else {
#pragma unroll
        for (int j = 0; j < 4; j++) {
            int idx = i0 + j;
            if (idx < NN) s += deg[idx];
        }
    }
#pragma unroll
    for (int off = 1; off < 64; off <<= 1) s += __shfl_xor(s, off);
    if (lane == 0) ws[wid] = s;
    __syncthreads();
    if (t == 0) partials[blockIdx.x] = ws[0] + ws[1] + ws[2] + ws[3];
}

// stage 2: one wave scans the 98 partials in place (inclusive -> exclusive)
__global__ void k_scanpart(int* __restrict__ partials, int* __restrict__ row_off) {
    const int lane = threadIdx.x & 63;
    int v0 = (lane < SCAN_B) ? partials[lane] : 0;
    int i1 = lane + 64;
    int v1 = (i1 < SCAN_B) ? partials[i1] : 0;
    int s0 = v0;
#pragma unroll
    for (int off = 1; off < 64; off <<= 1) {
        int n = __shfl_up(s0, off);
        if (lane >= off) s0 += n;
    }
    int tot0 = __shfl(s0, 63);
    int s1 = v1;
#pragma unroll
    for (int off = 1; off < 64; off <<= 1) {
        int n = __shfl_up(s1, off);
        if (lane >= off) s1 += n;
    }
    if (lane < SCAN_B) partials[lane] = s0 - v0;
    if (i1 < SCAN_B) partials[i1] = tot0 + s1 - v1;
    if (lane == 0) row_off[NN] = NE;  // total degree == edge count
}

// stage 3: per-block local scan + global offset, emit row_off & inv_deg
__global__ void __launch_bounds__(256) k_offsets(const int* __restrict__ deg,
                                                 const int* __restrict__ partials,
                                                 int* __restrict__ row_off,
                                                 float* __restrict__ inv_deg) {
    __shared__ int wsum[4];
    const int t = threadIdx.x, lane = t & 63, wid = t >> 6;
    int i0 = blockIdx.x * 1024 + t * 4;
    int v[4];
    int loc = 0;
#pragma unroll
    for (int j = 0; j < 4; j++) {
        int idx = i0 + j;
        v[j] = (idx < NN) ? deg[idx] : 0;
        loc += v[j];
    }
    int run = loc;
#pragma unroll
    for (int off = 1; off < 64; off <<= 1) {
        int n = __shfl_up(run, off);
        if (lane >= off) run += n;
    }
    if (lane == 63) wsum[wid] = run;
    __syncthreads();
    int woff = partials[blockIdx.x];
#pragma unroll
    for (int wv = 0; wv < 4; wv++)
        if (wv < wid) woff += wsum[wv];
    int excl = woff + run - loc;
#pragma unroll
    for (int j = 0; j < 4; j++) {
        int idx = i0 + j;
        if (idx < NN) {
            row_off[idx] = excl;
            inv_deg[idx] = 1.0f / fmaxf((float)v[j], 1.0f);
            excl += v[j];
        }
    }
}

__global__ void k_fill(const int* __restrict__ src, const int* __restrict__ dst,
                       const int* __restrict__ row_off, int* __restrict__ cursor,
                       int* __restrict__ col) {
    int e = blockIdx.x * blockDim.x + threadIdx.x;
    if (e < NE) {
        int d = dst[e];
        int p = atomicAdd(&cursor[d], 1);
        col[row_off[d] + p] = src[e];
    }
}

// ---------- fp32 -> bf16 convert (x) ----------
__global__ void k_cvt(const float* __restrict__ x, unsigned short* __restrict__ xb) {
    int t = blockIdx.x * blockDim.x + threadIdx.x;
    if (t >= NN * F / 8) return;
    const float4* x4 = (const float4*)x;
    float4 a = x4[t * 2], b = x4[t * 2 + 1];
    u16x8 o;
    o[0] = b16(a.x); o[1] = b16(a.y); o[2] = b16(a.z); o[3] = b16(a.w);
    o[4] = b16(b.x); o[5] = b16(b.y); o[6] = b16(b.z); o[7] = b16(b.w);
    ((u16x8*)xb)[t] = o;
}

// ---------- pack weights into MFMA-fragment-linear bf16 ----------
__global__ void k_pack_all(const float* __restrict__ Ws0, const float* __restrict__ Wn0,
                           const float* __restrict__ Ws1, const float* __restrict__ Wn1,
                           const float* __restrict__ Ws2, const float* __restrict__ Wn2,
                           unsigned short* __restrict__ wp) {
    int idx = blockIdx.x * blockDim.x + threadIdx.x;
    if (idx >= 77824) return;
    const float* W;
    int base, ncols;
    if (idx < 65536) {
        int m = idx >> 14;
        W = (m == 0) ? Ws0 : (m == 1) ? Wn0 : (m == 2) ? Ws1 : Wn1;
        base = m << 14;
        ncols = 128;
    } else {
        int m = (idx - 65536) / 6144;
        W = m ? Wn2 : Ws2;
        base = 65536 + m * 6144;
        ncols = NCLS;
    }
    int li = idx - base;
    int nt = li >> 11;
    int r = li & 2047;
    int kk = r >> 9;
    int r2 = r & 511;
    int lane = r2 >> 3;
    int j = r2 & 7;
    int k = kk * 32 + ((lane >> 4) << 3) + j;
    int n = nt * 16 + (lane & 15);
    float v = (n < ncols) ? W[k * ncols + n] : 0.f;
    wp[idx] = b16(v);
}

// ---------- mean aggregation: wave/node, col prefetch + shfl broadcast, MLP x8 ----------
__global__ void __launch_bounds__(256) k_aggb(const unsigned int* __restrict__ hb32,
                                              const int* __restrict__ row_off,
                                              const int* __restrict__ col,
                                              const float* __restrict__ inv_deg,
                                              unsigned int* __restrict__ ab32) {
    int node = (blockIdx.x * blockDim.x + threadIdx.x) >> 6;
    int lane = threadIdx.x & 63;
    if (node >= NN) return;
    int b = row_off[node], e = row_off[node + 1];
    int deg = e - b;
    float ax = 0.f, ay = 0.f;
    for (int base = 0; base < deg; base += 64) {
        int cnt = deg - base;
        if (cnt > 64) cnt = 64;
        int myc = col[b + base + (lane < cnt ? lane : 0)];
        for (int jj = 0; jj < cnt; jj += 8) {
            int cs[8];
            unsigned int us[8];
#pragma unroll
            for (int k = 0; k < 8; k++) {
                int idx = jj + k;
                cs[k] = __shfl(myc, idx < cnt ? idx : 0);
            }
#pragma unroll
            for (int k = 0; k < 8; k++) us[k] = hb32[(size_t)cs[k] * 64 + lane];
#pragma unroll
            for (int k = 0; k < 8; k++) {
                if (jj + k < cnt) {  // wave-uniform
                    ax += bflo(us[k]);
                    ay += bfhi(us[k]);
                }
            }
        }
    }
    float s = inv_deg[node];
    ax *= s; ay *= s;
    ab32[(size_t)node * 64 + lane] = (unsigned int)b16(ax) | ((unsigned int)b16(ay) << 16);
}

// ---------- fused dual-GEMM layer via MFMA ----------
template <bool RELU>
__global__ void __launch_bounds__(256) k_layer(const unsigned short* __restrict__ hb,
                                               const unsigned short* __restrict__ ab,
                                               const unsigned short* __restrict__ wps,
                                               const unsigned short* __restrict__ wpn,
                                               const float* __restrict__ bias,
                                               unsigned short* __restrict__ outb) {
    const int wid = threadIdx.x >> 6, lane = threadIdx.x & 63;
    const int tile0 = blockIdx.x * 64;
    const short8* ws8 = (const short8*)wps;
    const short8* wn8 = (const short8*)wpn;
    short8 wf[2][2][4];
#pragma unroll
    for (int t = 0; t < 2; t++) {
        int nt = 2 * wid + t;
#pragma unroll
        for (int kk = 0; kk < 4; kk++) {
            wf[0][t][kk] = ws8[(nt * 4 + kk) * 64 + lane];
            wf[1][t][kk] = wn8[(nt * 4 + kk) * 64 + lane];
        }
    }
    const int rb = lane & 15, kq = lane >> 4;
    float bv[2];
#pragma unroll
    for (int t = 0; t < 2; t++) bv[t] = bias[(2 * wid + t) * 16 + rb];
    const short8* h8 = (const short8*)hb;
    const short8* a8 = (const short8*)ab;
    f32x4 zero = {0.f, 0.f, 0.f, 0.f};
    f32x4 acc[4][2];
#pragma unroll
    for (int m = 0; m < 4; m++)
#pragma unroll
        for (int t = 0; t < 2; t++) acc[m][t] = zero;
#pragma unroll
    for (int kk = 0; kk < 4; kk++) {
#pragma unroll
        for (int m = 0; m < 4; m++) {
            int row = tile0 + m * 16 + rb;
            int rc = row < NN ? row : NN - 1;
            int idx = rc * 16 + kk * 4 + kq;
            short8 af = h8[idx];
            short8 gf = a8[idx];
            acc[m][0] = MFMA16(af, wf[0][0][kk], acc[m][0]);
            acc[m][1] = MFMA16(af, wf[0][1][kk], acc[m][1]);
            acc[m][0] = MFMA16(gf, wf[1][0][kk], acc[m][0]);
            acc[m][1] = MFMA16(gf, wf[1][1][kk], acc[m][1]);
        }
    }
#pragma unroll
    for (int m = 0; m < 4; m++) {
#pragma unroll
        for (int reg = 0; reg < 4; reg++) {
            int row = tile0 + m * 16 + kq * 4 + reg;
            if (row < NN) {
#pragma unroll
                for (int t = 0; t < 2; t++) {
                    float v = acc[m][t][reg] + bv[t];
                    if (RELU) v = fmaxf(v, 0.f);
                    outb[(size_t)row * F + (2 * wid + t) * 16 + rb] = b16(v);
                }
            }
        }
    }
}

// ---------- final layer: MFMA (N=48) + log_softmax, fp32 out ----------
__global__ void __launch_bounds__(512) k_out(const unsigned short* __restrict__ hb,
                                             const unsigned short* __restrict__ ab,
                                             const unsigned short* __restrict__ wps,
                                             const unsigned short* __restrict__ wpn,
                                             const float* __restrict__ bias,
                                             float* __restrict__ out) {
    const int wid = threadIdx.x >> 6, lane = threadIdx.x & 63;
    const int R0 = blockIdx.x * 128 + wid * 16;
    const short8* ws8 = (const short8*)wps;
    const short8* wn8 = (const short8*)wpn;
    short8 wf[2][3][4];
#pragma unroll
    for (int nt = 0; nt < 3; nt++)
#pragma unroll
        for (int kk = 0; kk < 4; kk++) {
            wf[0][nt][kk] = ws8[(nt * 4 + kk) * 64 + lane];
            wf[1][nt][kk] = wn8[(nt * 4 + kk) * 64 + lane];
        }
    const int rb = lane & 15, kq = lane >> 4;
    float bv[3];
    bool valid[3];
#pragma unroll
    for (int nt = 0; nt < 3; nt++) {
        int c = nt * 16 + rb;
        valid[nt] = c < NCLS;
        bv[nt] = valid[nt] ? bias[c] : 0.f;
    }
    const short8* h8 = (const short8*)hb;
    const short8* a8 = (const short8*)ab;
    f32x4 zero = {0.f, 0.f, 0.f, 0.f};
    f32x4 acc[3] = {zero, zero, zero};
    int rowr = R0 + rb;
    int rc = rowr < NN ? rowr : NN - 1;
#pragma unroll
    for (int kk = 0; kk < 4; kk++) {
        int idx = rc * 16 + kk * 4 + kq;
        short8 af = h8[idx];
        short8 gf = a8[idx];
#pragma unroll
        for (int nt = 0; nt < 3; nt++) {
            acc[nt] = MFMA16(af, wf[0][nt][kk], acc[nt]);
            acc[nt] = MFMA16(gf, wf[1][nt][kk], acc[nt]);
        }
    }
#pragma unroll
    for (int reg = 0; reg < 4; reg++) {
        int row = R0 + kq * 4 + reg;
        float v[3];
        float mx = -1e30f;
#pragma unroll
        for (int nt = 0; nt < 3; nt++) {
            v[nt] = acc[nt][reg] + bv[nt];
            if (valid[nt]) mx = fmaxf(mx, v[nt]);
        }
        for (int off = 1; off < 16; off <<= 1) mx = fmaxf(mx, __shfl_xor(mx, off));
        float s = 0.f;
#pragma unroll
        for (int nt = 0; nt < 3; nt++)
            if (valid[nt]) s += expf(v[nt] - mx);
        for (int off = 1; off < 16; off <<= 1) s += __shfl_xor(s, off);
        float L = mx + logf(s);
        if (row < NN) {
#pragma unroll
            for (int nt = 0; nt < 3; nt++)
                if (valid[nt]) out[(size_t)row * NCLS + nt * 16 + rb] = v[nt] - L;
        }
    }
}

extern "C" void kernel_launch(void* const* d_in, const int* in_sizes, int n_in,
                              void* d_out, int out_size, void* d_ws, size_t ws_size,
                              hipStream_t stream) {
    (void)in_sizes; (void)n_in; (void)out_size; (void)ws_size;
    const float* x = (const float*)d_in[0];
    const int* src = (const int*)d_in[1];
    const int* dst = (const int*)d_in[2];
    const float* Ws0 = (const float*)d_in[3];
    const float* Wn0 = (const float*)d_in[4];
    const float* b0 = (const float*)d_in[5];
    const float* Ws1 = (const float*)d_in[6];
    const float* Wn1 = (const float*)d_in[7];
    const float* b1 = (const float*)d_in[8];
    const float* Ws2 = (const float*)d_in[9];
    const float* Wn2 = (const float*)d_in[10];
    const float* b2 = (const float*)d_in[11];
    float* out = (float*)d_out;

    char* w = (char*)d_ws;
    size_t off = 0;
    auto alloc = [&](size_t bytes) -> char* {
        char* p = w + off;
        off = (off + bytes + 255) & ~(size_t)255;
        return p;
    };
    int* deg = (int*)alloc((size_t)NN * 4);
    int* row_off = (int*)alloc((size_t)(NN + 1) * 4);
    int* cursor = (int*)alloc((size_t)NN * 4);
    int* col = (int*)alloc((size_t)NE * 4);
    float* inv_deg = (float*)alloc((size_t)NN * 4);
    int* partials = (int*)alloc((size_t)SCAN_B * 4);
    unsigned short* xb = (unsigned short*)alloc((size_t)NN * F * 2);
    unsigned short* aggb = (unsigned short*)alloc((size_t)NN * F * 2);
    unsigned short* h1b = (unsigned short*)alloc((size_t)NN * F * 2);
    unsigned short* h2b = (unsigned short*)alloc((size_t)NN * F * 2);
    unsigned short* wp = (unsigned short*)alloc((size_t)77824 * 2);

    hipMemsetAsync(deg, 0, (size_t)NN * 4, stream);
    hipMemsetAsync(cursor, 0, (size_t)NN * 4, stream);

    const int EB = (NE + 255) / 256;
    k_deg<<<EB, 256, 0, stream>>>(dst, deg);
    k_part<<<SCAN_B, 256, 0, stream>>>(deg, partials);
    k_scanpart<<<1, 64, 0, stream>>>(partials, row_off);
    k_offsets<<<SCAN_B, 256, 0, stream>>>(deg, partials, row_off, inv_deg);
    k_fill<<<EB, 256, 0, stream>>>(src, dst, row_off, cursor, col);
    k_cvt<<<(NN * F / 8 + 255) / 256, 256, 0, stream>>>(x, xb);
    k_pack_all<<<(77824 + 255) / 256, 256, 0, stream>>>(Ws0, Wn0, Ws1, Wn1, Ws2, Wn2, wp);

    unsigned short* wS0 = wp;
    unsigned short* wN0 = wp + 16384;
    unsigned short* wS1 = wp + 32768;
    unsigned short* wN1 = wp + 49152;
    unsigned short* wS2 = wp + 65536;
    unsigned short* wN2 = wp + 71680;

    const int AGG_B = NN * 64 / 256;            // 25000 (wave per node)
    const int LYR_B = (NN + 63) / 64;           // 1563
    const int OUT_B = (NN + 127) / 128;         // 782

    // layer 0
    k_aggb<<<AGG_B, 256, 0, stream>>>((const unsigned int*)xb, row_off, col, inv_deg,
                                      (unsigned int*)aggb);
    k_layer<true><<<LYR_B, 256, 0, stream>>>(xb, aggb, wS0, wN0, b0, h1b);
    // layer 1
    k_aggb<<<AGG_B, 256, 0, stream>>>((const unsigned int*)h1b, row_off, col, inv_deg,
                                      (unsigned int*)aggb);
    k_layer<true><<<LYR_B, 256, 0, stream>>>(h1b, aggb, wS1, wN1, b1, h2b);
    // layer 2
    k_aggb<<<AGG_B, 256, 0, stream>>>((const unsigned int*)h2b, row_off, col, inv_deg,
                                      (unsigned int*)aggb);
    k_out<<<OUT_B, 512, 0, stream>>>(h2b, aggb, wS2, wN2, b2, out);
}

// Round 7
// 352.281 us; speedup vs baseline: 6.0382x; 1.3312x over previous
//
#include <hip/hip_runtime.h>
#include <hip/hip_bf16.h>

#define NN 100000
#define NE 1600000
#define F 128
#define NCLS 47

#define SCAN_B 98      // ceil(NN / 1024) for node-level scan
#define NPB 256        // nodes per bucket (d >> 8)
#define BUCKETS 391    // ceil(NN / NPB)
#define ABLK 512       // phase-A blocks
#define ACHUNK (NE / ABLK)  // 3125 edges per A-block

typedef __attribute__((ext_vector_type(8))) short short8;
typedef __attribute__((ext_vector_type(8))) unsigned short u16x8;
typedef __attribute__((ext_vector_type(4))) float f32x4;

#define MFMA16(A, B, C) __builtin_amdgcn_mfma_f32_16x16x32_bf16(A, B, C, 0, 0, 0)

__device__ __forceinline__ unsigned short b16(float f) {
    unsigned int u = __builtin_bit_cast(unsigned int, f);
    unsigned int r = u + 0x7FFFu + ((u >> 16) & 1u);  // RTN-even
    return (unsigned short)(r >> 16);
}
__device__ __forceinline__ float bflo(unsigned int u) { return __builtin_bit_cast(float, u << 16); }
__device__ __forceinline__ float bfhi(unsigned int u) { return __builtin_bit_cast(float, u & 0xFFFF0000u); }

// ---------- CSR build, phase A: bucket the edges ----------
// A1: per-block LDS histogram of dst buckets -> global bucket_cnt
__global__ void __launch_bounds__(256) k_bhist(const int* __restrict__ dst,
                                               int* __restrict__ bucket_cnt) {
    __shared__ int hist[BUCKETS];
    const int t = threadIdx.x;
    for (int i = t; i < BUCKETS; i += 256) hist[i] = 0;
    __syncthreads();
    const int e0 = blockIdx.x * ACHUNK;
    for (int i = t; i < ACHUNK; i += 256) atomicAdd(&hist[dst[e0 + i] >> 8], 1);
    __syncthreads();
    for (int i = t; i < BUCKETS; i += 256)
        if (hist[i]) atomicAdd(&bucket_cnt[i], hist[i]);
}

// A2: one wave scans bucket_cnt -> bucket_off (with sentinel) and cursor copy
__global__ void k_bscan(const int* __restrict__ bucket_cnt, int* __restrict__ bucket_off,
                        int* __restrict__ cursor) {
    const int lane = threadIdx.x & 63;
    int run = 0;
#pragma unroll
    for (int c = 0; c < 7; c++) {
        int idx = c * 64 + lane;
        int v = (idx < BUCKETS) ? bucket_cnt[idx] : 0;
        int s = v;
#pragma unroll
        for (int off = 1; off < 64; off <<= 1) {
            int n = __shfl_up(s, off);
            if (lane >= off) s += n;
        }
        int excl = run + s - v;
        if (idx <= BUCKETS) {
            bucket_off[idx] = excl;
            cursor[idx] = excl;
        }
        run += __shfl(s, 63);
    }
}

// A3: scatter (src,dst) into bucket-contiguous ebuf
__global__ void __launch_bounds__(256) k_bscatter(const int* __restrict__ src,
                                                  const int* __restrict__ dst,
                                                  int* __restrict__ cursor,
                                                  int2* __restrict__ ebuf) {
    __shared__ int hist[BUCKETS];
    __shared__ int base[BUCKETS];
    __shared__ int rank[BUCKETS];
    const int t = threadIdx.x;
    for (int i = t; i < BUCKETS; i += 256) {
        hist[i] = 0;
        rank[i] = 0;
    }
    __syncthreads();
    const int e0 = blockIdx.x * ACHUNK;
    for (int i = t; i < ACHUNK; i += 256) atomicAdd(&hist[dst[e0 + i] >> 8], 1);
    __syncthreads();
    for (int i = t; i < BUCKETS; i += 256) {
        int h = hist[i];
        base[i] = h ? atomicAdd(&cursor[i], h) : 0;
    }
    __syncthreads();
    for (int i = t; i < ACHUNK; i += 256) {
        int s = src[e0 + i];
        int d = dst[e0 + i];
        int b = d >> 8;
        int r = atomicAdd(&rank[b], 1);
        ebuf[base[b] + r] = make_int2(s, d);
    }
}

// ---------- CSR build, phase B: per-bucket (256 nodes) ----------
// B1: node-level degree via LDS histogram (no global atomics)
__global__ void __launch_bounds__(256) k_bdeg(const int2* __restrict__ ebuf,
                                              const int* __restrict__ bucket_off,
                                              int* __restrict__ deg) {
    __shared__ int cnt[NPB];
    const int t = threadIdx.x;
    cnt[t] = 0;
    __syncthreads();
    const int e0 = bucket_off[blockIdx.x], e1 = bucket_off[blockIdx.x + 1];
    for (int i = e0 + t; i < e1; i += 256) atomicAdd(&cnt[ebuf[i].y & 255], 1);
    __syncthreads();
    int node = (blockIdx.x << 8) + t;
    if (node < NN) deg[node] = cnt[t];
}

// B2: fill col with LDS cursors + LDS-cached row_off
__global__ void __launch_bounds__(256) k_bfill(const int2* __restrict__ ebuf,
                                               const int* __restrict__ bucket_off,
                                               const int* __restrict__ row_off,
                                               int* __restrict__ col) {
    __shared__ int ro[NPB];
    __shared__ int cur[NPB];
    const int t = threadIdx.x;
    int node = (blockIdx.x << 8) + t;
    ro[t] = (node < NN) ? row_off[node] : 0;
    cur[t] = 0;
    __syncthreads();
    const int e0 = bucket_off[blockIdx.x], e1 = bucket_off[blockIdx.x + 1];
    for (int i = e0 + t; i < e1; i += 256) {
        int2 e = ebuf[i];
        int d = e.y & 255;
        int p = atomicAdd(&cur[d], 1);
        col[ro[d] + p] = e.x;
    }
}

// ---------- node-level scan (row_off, inv_deg) ----------
__global__ void __launch_bounds__(256) k_part(const int* __restrict__ deg,
                                              int* __restrict__ partials) {
    __shared__ int ws[4];
    const int t = threadIdx.x, lane = t & 63, wid = t >> 6;
    int i0 = blockIdx.x * 1024 + t * 4;
    int s = 0;
    if (i0 + 3 < NN) {
        int4 v = *(const int4*)&deg[i0];
        s = v.x + v.y + v.z + v.w;
    } else {
#pragma unroll
        for (int j = 0; j < 4; j++) {
            int idx = i0 + j;
            if (idx < NN) s += deg[idx];
        }
    }
#pragma unroll
    for (int off = 1; off < 64; off <<= 1) s += __shfl_xor(s, off);
    if (lane == 0) ws[wid] = s;
    __syncthreads();
    if (t == 0) partials[blockIdx.x] = ws[0] + ws[1] + ws[2] + ws[3];
}

__global__ void k_scanpart(int* __restrict__ partials, int* __restrict__ row_off) {
    const int lane = threadIdx.x & 63;
    int v0 = (lane < SCAN_B) ? partials[lane] : 0;
    int i1 = lane + 64;
    int v1 = (i1 < SCAN_B) ? partials[i1] : 0;
    int s0 = v0;
#pragma unroll
    for (int off = 1; off < 64; off <<= 1) {
        int n = __shfl_up(s0, off);
        if (lane >= off) s0 += n;
    }
    int tot0 = __shfl(s0, 63);
    int s1 = v1;
#pragma unroll
    for (int off = 1; off < 64; off <<= 1) {
        int n = __shfl_up(s1, off);
        if (lane >= off) s1 += n;
    }
    if (lane < SCAN_B) partials[lane] = s0 - v0;
    if (i1 < SCAN_B) partials[i1] = tot0 + s1 - v1;
    if (lane == 0) row_off[NN] = NE;
}

__global__ void __launch_bounds__(256) k_offsets(const int* __restrict__ deg,
                                                 const int* __restrict__ partials,
                                                 int* __restrict__ row_off,
                                                 float* __restrict__ inv_deg) {
    __shared__ int wsum[4];
    const int t = threadIdx.x, lane = t & 63, wid = t >> 6;
    int i0 = blockIdx.x * 1024 + t * 4;
    int v[4];
    int loc = 0;
#pragma unroll
    for (int j = 0; j < 4; j++) {
        int idx = i0 + j;
        v[j] = (idx < NN) ? deg[idx] : 0;
        loc += v[j];
    }
    int run = loc;
#pragma unroll
    for (int off = 1; off < 64; off <<= 1) {
        int n = __shfl_up(run, off);
        if (lane >= off) run += n;
    }
    if (lane == 63) wsum[wid] = run;
    __syncthreads();
    int woff = partials[blockIdx.x];
#pragma unroll
    for (int wv = 0; wv < 4; wv++)
        if (wv < wid) woff += wsum[wv];
    int excl = woff + run - loc;
#pragma unroll
    for (int j = 0; j < 4; j++) {
        int idx = i0 + j;
        if (idx < NN) {
            row_off[idx] = excl;
            inv_deg[idx] = 1.0f / fmaxf((float)v[j], 1.0f);
            excl += v[j];
        }
    }
}

// ---------- fp32 -> bf16 convert (x) ----------
__global__ void k_cvt(const float* __restrict__ x, unsigned short* __restrict__ xb) {
    int t = blockIdx.x * blockDim.x + threadIdx.x;
    if (t >= NN * F / 8) return;
    const float4* x4 = (const float4*)x;
    float4 a = x4[t * 2], b = x4[t * 2 + 1];
    u16x8 o;
    o[0] = b16(a.x); o[1] = b16(a.y); o[2] = b16(a.z); o[3] = b16(a.w);
    o[4] = b16(b.x); o[5] = b16(b.y); o[6] = b16(b.z); o[7] = b16(b.w);
    ((u16x8*)xb)[t] = o;
}

// ---------- pack weights into MFMA-fragment-linear bf16 ----------
__global__ void k_pack_all(const float* __restrict__ Ws0, const float* __restrict__ Wn0,
                           const float* __restrict__ Ws1, const float* __restrict__ Wn1,
                           const float* __restrict__ Ws2, const float* __restrict__ Wn2,
                           unsigned short* __restrict__ wp) {
    int idx = blockIdx.x * blockDim.x + threadIdx.x;
    if (idx >= 77824) return;
    const float* W;
    int base, ncols;
    if (idx < 65536) {
        int m = idx >> 14;
        W = (m == 0) ? Ws0 : (m == 1) ? Wn0 : (m == 2) ? Ws1 : Wn1;
        base = m << 14;
        ncols = 128;
    } else {
        int m = (idx - 65536) / 6144;
        W = m ? Wn2 : Ws2;
        base = 65536 + m * 6144;
        ncols = NCLS;
    }
    int li = idx - base;
    int nt = li >> 11;
    int r = li & 2047;
    int kk = r >> 9;
    int r2 = r & 511;
    int lane = r2 >> 3;
    int j = r2 & 7;
    int k = kk * 32 + ((lane >> 4) << 3) + j;
    int n = nt * 16 + (lane & 15);
    float v = (n < ncols) ? W[k * ncols + n] : 0.f;
    wp[idx] = b16(v);
}

// ---------- mean aggregation: wave/node, col prefetch + shfl broadcast, MLP x8 ----------
__global__ void __launch_bounds__(256) k_aggb(const unsigned int* __restrict__ hb32,
                                              const int* __restrict__ row_off,
                                              const int* __restrict__ col,
                                              const float* __restrict__ inv_deg,
                                              unsigned int* __restrict__ ab32) {
    int node = (blockIdx.x * blockDim.x + threadIdx.x) >> 6;
    int lane = threadIdx.x & 63;
    if (node >= NN) return;
    int b = row_off[node], e = row_off[node + 1];
    int deg = e - b;
    float ax = 0.f, ay = 0.f;
    for (int base = 0; base < deg; base += 64) {
        int cnt = deg - base;
        if (cnt > 64) cnt = 64;
        int myc = col[b + base + (lane < cnt ? lane : 0)];
        for (int jj = 0; jj < cnt; jj += 8) {
            int cs[8];
            unsigned int us[8];
#pragma unroll
            for (int k = 0; k < 8; k++) {
                int idx = jj + k;
                cs[k] = __shfl(myc, idx < cnt ? idx : 0);
            }
#pragma unroll
            for (int k = 0; k < 8; k++) us[k] = hb32[(size_t)cs[k] * 64 + lane];
#pragma unroll
            for (int k = 0; k < 8; k++) {
                if (jj + k < cnt) {  // wave-uniform
                    ax += bflo(us[k]);
                    ay += bfhi(us[k]);
                }
            }
        }
    }
    float s = inv_deg[node];
    ax *= s; ay *= s;
    ab32[(size_t)node * 64 + lane] = (unsigned int)b16(ax) | ((unsigned int)b16(ay) << 16);
}

// ---------- fused dual-GEMM layer via MFMA ----------
template <bool RELU>
__global__ void __launch_bounds__(256) k_layer(const unsigned short* __restrict__ hb,
                                               const unsigned short* __restrict__ ab,
                                               const unsigned short* __restrict__ wps,
                                               const unsigned short* __restrict__ wpn,
                                               const float* __restrict__ bias,
                                               unsigned short* __restrict__ outb) {
    const int wid = threadIdx.x >> 6, lane = threadIdx.x & 63;
    const int tile0 = blockIdx.x * 64;
    const short8* ws8 = (const short8*)wps;
    const short8* wn8 = (const short8*)wpn;
    short8 wf[2][2][4];
#pragma unroll
    for (int t = 0; t < 2; t++) {
        int nt = 2 * wid + t;
#pragma unroll
        for (int kk = 0; kk < 4; kk++) {
            wf[0][t][kk] = ws8[(nt * 4 + kk) * 64 + lane];
            wf[1][t][kk] = wn8[(nt * 4 + kk) * 64 + lane];
        }
    }
    const int rb = lane & 15, kq = lane >> 4;
    float bv[2];
#pragma unroll
    for (int t = 0; t < 2; t++) bv[t] = bias[(2 * wid + t) * 16 + rb];
    const short8* h8 = (const short8*)hb;
    const short8* a8 = (const short8*)ab;
    f32x4 zero = {0.f, 0.f, 0.f, 0.f};
    f32x4 acc[4][2];
#pragma unroll
    for (int m = 0; m < 4; m++)
#pragma unroll
        for (int t = 0; t < 2; t++) acc[m][t] = zero;
#pragma unroll
    for (int kk = 0; kk < 4; kk++) {
#pragma unroll
        for (int m = 0; m < 4; m++) {
            int row = tile0 + m * 16 + rb;
            int rc = row < NN ? row : NN - 1;
            int idx = rc * 16 + kk * 4 + kq;
            short8 af = h8[idx];
            short8 gf = a8[idx];
            acc[m][0] = MFMA16(af, wf[0][0][kk], acc[m][0]);
            acc[m][1] = MFMA16(af, wf[0][1][kk], acc[m][1]);
            acc[m][0] = MFMA16(gf, wf[1][0][kk], acc[m][0]);
            acc[m][1] = MFMA16(gf, wf[1][1][kk], acc[m][1]);
        }
    }
#pragma unroll
    for (int m = 0; m < 4; m++) {
#pragma unroll
        for (int reg = 0; reg < 4; reg++) {
            int row = tile0 + m * 16 + kq * 4 + reg;
            if (row < NN) {
#pragma unroll
                for (int t = 0; t < 2; t++) {
                    float v = acc[m][t][reg] + bv[t];
                    if (RELU) v = fmaxf(v, 0.f);
                    outb[(size_t)row * F + (2 * wid + t) * 16 + rb] = b16(v);
                }
            }
        }
    }
}

// ---------- final layer: MFMA (N=48) + log_softmax, fp32 out ----------
__global__ void __launch_bounds__(512) k_out(const unsigned short* __restrict__ hb,
                                             const unsigned short* __restrict__ ab,
                                             const unsigned short* __restrict__ wps,
                                             const unsigned short* __restrict__ wpn,
                                             const float* __restrict__ bias,
                                             float* __restrict__ out) {
    const int wid = threadIdx.x >> 6, lane = threadIdx.x & 63;
    const int R0 = blockIdx.x * 128 + wid * 16;
    const short8* ws8 = (const short8*)wps;
    const short8* wn8 = (const short8*)wpn;
    short8 wf[2][3][4];
#pragma unroll
    for (int nt = 0; nt < 3; nt++)
#pragma unroll
        for (int kk = 0; kk < 4; kk++) {
            wf[0][nt][kk] = ws8[(nt * 4 + kk) * 64 + lane];
            wf[1][nt][kk] = wn8[(nt * 4 + kk) * 64 + lane];
        }
    const int rb = lane & 15, kq = lane >> 4;
    float bv[3];
    bool valid[3];
#pragma unroll
    for (int nt = 0; nt < 3; nt++) {
        int c = nt * 16 + rb;
        valid[nt] = c < NCLS;
        bv[nt] = valid[nt] ? bias[c] : 0.f;
    }
    const short8* h8 = (const short8*)hb;
    const short8* a8 = (const short8*)ab;
    f32x4 zero = {0.f, 0.f, 0.f, 0.f};
    f32x4 acc[3] = {zero, zero, zero};
    int rowr = R0 + rb;
    int rc = rowr < NN ? rowr : NN - 1;
#pragma unroll
    for (int kk = 0; kk < 4; kk++) {
        int idx = rc * 16 + kk * 4 + kq;
        short8 af = h8[idx];
        short8 gf = a8[idx];
#pragma unroll
        for (int nt = 0; nt < 3; nt++) {
            acc[nt] = MFMA16(af, wf[0][nt][kk], acc[nt]);
            acc[nt] = MFMA16(gf, wf[1][nt][kk], acc[nt]);
        }
    }
#pragma unroll
    for (int reg = 0; reg < 4; reg++) {
        int row = R0 + kq * 4 + reg;
        float v[3];
        float mx = -1e30f;
#pragma unroll
        for (int nt = 0; nt < 3; nt++) {
            v[nt] = acc[nt][reg] + bv[nt];
            if (valid[nt]) mx = fmaxf(mx, v[nt]);
        }
        for (int off = 1; off < 16; off <<= 1) mx = fmaxf(mx, __shfl_xor(mx, off));
        float s = 0.f;
#pragma unroll
        for (int nt = 0; nt < 3; nt++)
            if (valid[nt]) s += expf(v[nt] - mx);
        for (int off = 1; off < 16; off <<= 1) s += __shfl_xor(s, off);
        float L = mx + logf(s);
        if (row < NN) {
#pragma unroll
            for (int nt = 0; nt < 3; nt++)
                if (valid[nt]) out[(size_t)row * NCLS + nt * 16 + rb] = v[nt] - L;
        }
    }
}

extern "C" void kernel_launch(void* const* d_in, const int* in_sizes, int n_in,
                              void* d_out, int out_size, void* d_ws, size_t ws_size,
                              hipStream_t stream) {
    (void)in_sizes; (void)n_in; (void)out_size; (void)ws_size;
    const float* x = (const float*)d_in[0];
    const int* src = (const int*)d_in[1];
    const int* dst = (const int*)d_in[2];
    const float* Ws0 = (const float*)d_in[3];
    const float* Wn0 = (const float*)d_in[4];
    const float* b0 = (const float*)d_in[5];
    const float* Ws1 = (const float*)d_in[6];
    const float* Wn1 = (const float*)d_in[7];
    const float* b1 = (const float*)d_in[8];
    const float* Ws2 = (const float*)d_in[9];
    const float* Wn2 = (const float*)d_in[10];
    const float* b2 = (const float*)d_in[11];
    float* out = (float*)d_out;

    char* w = (char*)d_ws;
    size_t off = 0;
    auto alloc = [&](size_t bytes) -> char* {
        char* p = w + off;
        off = (off + bytes + 255) & ~(size_t)255;
        return p;
    };
    int* deg = (int*)alloc((size_t)NN * 4);
    int* row_off = (int*)alloc((size_t)(NN + 1) * 4);
    int* col = (int*)alloc((size_t)NE * 4);
    float* inv_deg = (float*)alloc((size_t)NN * 4);
    int* partials = (int*)alloc((size_t)SCAN_B * 4);
    int* bucket_cnt = (int*)alloc((size_t)(BUCKETS + 1) * 4);
    int* bucket_off = (int*)alloc((size_t)(BUCKETS + 1) * 4);
    int* bcursor = (int*)alloc((size_t)(BUCKETS + 1) * 4);
    int2* ebuf = (int2*)alloc((size_t)NE * 8);
    unsigned short* xb = (unsigned short*)alloc((size_t)NN * F * 2);
    unsigned short* aggb = (unsigned short*)alloc((size_t)NN * F * 2);
    unsigned short* h1b = (unsigned short*)alloc((size_t)NN * F * 2);
    unsigned short* h2b = (unsigned short*)alloc((size_t)NN * F * 2);
    unsigned short* wp = (unsigned short*)alloc((size_t)77824 * 2);

    hipMemsetAsync(bucket_cnt, 0, (size_t)(BUCKETS + 1) * 4, stream);

    // CSR build: bucket edges, then per-bucket deg/fill
    k_bhist<<<ABLK, 256, 0, stream>>>(dst, bucket_cnt);
    k_bscan<<<1, 64, 0, stream>>>(bucket_cnt, bucket_off, bcursor);
    k_bscatter<<<ABLK, 256, 0, stream>>>(src, dst, bcursor, ebuf);
    k_bdeg<<<BUCKETS, 256, 0, stream>>>(ebuf, bucket_off, deg);
    k_part<<<SCAN_B, 256, 0, stream>>>(deg, partials);
    k_scanpart<<<1, 64, 0, stream>>>(partials, row_off);
    k_offsets<<<SCAN_B, 256, 0, stream>>>(deg, partials, row_off, inv_deg);
    k_bfill<<<BUCKETS, 256, 0, stream>>>(ebuf, bucket_off, row_off, col);

    k_cvt<<<(NN * F / 8 + 255) / 256, 256, 0, stream>>>(x, xb);
    k_pack_all<<<(77824 + 255) / 256, 256, 0, stream>>>(Ws0, Wn0, Ws1, Wn1, Ws2, Wn2, wp);

    unsigned short* wS0 = wp;
    unsigned short* wN0 = wp + 16384;
    unsigned short* wS1 = wp + 32768;
    unsigned short* wN1 = wp + 49152;
    unsigned short* wS2 = wp + 65536;
    unsigned short* wN2 = wp + 71680;

    const int AGG_B = NN * 64 / 256;            // 25000 (wave per node)
    const int LYR_B = (NN + 63) / 64;           // 1563
    const int OUT_B = (NN + 127) / 128;         // 782

    // layer 0
    k_aggb<<<AGG_B, 256, 0, stream>>>((const unsigned int*)xb, row_off, col, inv_deg,
                                      (unsigned int*)aggb);
    k_layer<true><<<LYR_B, 256, 0, stream>>>(xb, aggb, wS0, wN0, b0, h1b);
    // layer 1
    k_aggb<<<AGG_B, 256, 0, stream>>>((const unsigned int*)h1b, row_off, col, inv_deg,
                                      (unsigned int*)aggb);
    k_layer<true><<<LYR_B, 256, 0, stream>>>(h1b, aggb, wS1, wN1, b1, h2b);
    // layer 2
    k_aggb<<<AGG_B, 256, 0, stream>>>((const unsigned int*)h2b, row_off, col, inv_deg,
                                      (unsigned int*)aggb);
    k_out<<<OUT_B, 512, 0, stream>>>(h2b, aggb, wS2, wN2, b2, out);
}